// Round 3
// baseline (260.918 us; speedup 1.0000x reference)
//
#include <hip/hip_runtime.h>
#include <hip/hip_bf16.h>

#define N_NODES 50000
#define N_EDGES 800000
#define NBKT 196           // ceil(50000/256) buckets of 256 nodes
#define ACHUNK 4096        // edges per block in binning kernels
#define AB 196             // ceil(800000/4096) histogram blocks
#define CASTB 6250         // 50000*128/4 float4 chunks / 256 threads
#define MG32 1563          // ceil(50000/32) aggemm row-tiles

typedef unsigned short u16;
typedef short v8s __attribute__((ext_vector_type(8)));
typedef float v4f __attribute__((ext_vector_type(4)));

__device__ __forceinline__ u16 f2bf(float f){
  union { float f; unsigned u; } x; x.f = f;
  unsigned u = x.u;
  return (u16)((u + 0x7FFFu + ((u >> 16) & 1u)) >> 16);   // RNE
}
__device__ __forceinline__ float lo_bf(unsigned u){
  union { unsigned u; float f; } x; x.u = u << 16; return x.f;
}
__device__ __forceinline__ float hi_bf(unsigned u){
  union { unsigned u; float f; } x; x.u = u & 0xffff0000u; return x.f;
}

// ---------------- fused prep: cast x->bf16, 3x weight transpose, A1 partial hists
// WT layout (stacked-K): WT[n*256 + k] = (k<128 ? Wl[k][n] : Wr[k-128][n]).
// out = [h | mean_h] @ [Wl; Wr]  — aggregation commutes with the linear map.

__device__ __forceinline__ void wprep(const float* __restrict__ Wl,
                                      const float* __restrict__ Wr,
                                      u16* __restrict__ WT, int N1, int idx){
  int n = idx >> 8, k = idx & 255;
  float v = (k < 128) ? Wl[k * N1 + n] : Wr[(k - 128) * N1 + n];
  WT[n * 256 + k] = f2bf(v);
}

__global__ __launch_bounds__(256) void k_prep_a1(const float* __restrict__ x,
                                                 u16* __restrict__ Xb,
                                                 const float* __restrict__ Wl1,
                                                 const float* __restrict__ Wr1,
                                                 const float* __restrict__ Wl2,
                                                 const float* __restrict__ Wr2,
                                                 const float* __restrict__ Wl3,
                                                 const float* __restrict__ Wr3,
                                                 u16* __restrict__ WT1,
                                                 u16* __restrict__ WT2,
                                                 u16* __restrict__ WT3,
                                                 const int* __restrict__ edges,
                                                 int* __restrict__ bpart){
  __shared__ int h[NBKT];
  int b = blockIdx.x, tid = threadIdx.x;
  if (b < CASTB){
    int i = b * 256 + tid;                       // exact: 6250*256 = 1.6M float4
    float4 v = ((const float4*)x)[i];
    ((ushort4*)Xb)[i] = make_ushort4(f2bf(v.x), f2bf(v.y), f2bf(v.z), f2bf(v.w));
  } else if (b < CASTB + 128){
    wprep(Wl1, Wr1, WT1, 128, (b - CASTB) * 256 + tid);        // 128*256 elems
  } else if (b < CASTB + 256){
    wprep(Wl2, Wr2, WT2, 128, (b - CASTB - 128) * 256 + tid);  // 128*256 elems
  } else if (b < CASTB + 320){
    wprep(Wl3, Wr3, WT3, 64, (b - CASTB - 256) * 256 + tid);   // 64*256 elems
  } else {
    int ab = b - (CASTB + 320);                  // 0..AB-1
    for (int i = tid; i < NBKT; i += 256) h[i] = 0;
    __syncthreads();
    int base = ab * ACHUNK;
    for (int i = tid; i < ACHUNK; i += 256){
      int j = base + i;
      if (j < N_EDGES) atomicAdd(&h[edges[N_EDGES + j] >> 8], 1);
    }
    __syncthreads();
    for (int i = tid; i < NBKT; i += 256) bpart[ab * NBKT + i] = h[i];
  }
}

// reduce partial hists + scan -> bbase (exclusive, +total), init bcur
__global__ __launch_bounds__(256) void k_scanb(const int* __restrict__ bpart,
                                               int* __restrict__ bbase,
                                               int* __restrict__ bcur){
  __shared__ int s[256];
  int tid = threadIdx.x;
  int v = 0;
  if (tid < NBKT){
    int a0 = 0, a1 = 0, a2 = 0, a3 = 0;
    int r = 0;
    for (; r + 4 <= AB; r += 4){
      a0 += bpart[(r    ) * NBKT + tid];
      a1 += bpart[(r + 1) * NBKT + tid];
      a2 += bpart[(r + 2) * NBKT + tid];
      a3 += bpart[(r + 3) * NBKT + tid];
    }
    for (; r < AB; ++r) a0 += bpart[r * NBKT + tid];
    v = (a0 + a1) + (a2 + a3);
  }
  s[tid] = v; __syncthreads();
  for (int d = 1; d < 256; d <<= 1){
    int t = (tid >= d) ? s[tid - d] : 0;
    __syncthreads();
    s[tid] += t;
    __syncthreads();
  }
  if (tid < NBKT){ bbase[tid] = s[tid] - v; bcur[tid] = s[tid] - v; }
  if (tid == NBKT - 1) bbase[NBKT] = s[tid];
}

// bucket-major scatter; pair packed as (src<<8) | (dst & 255)  (src<2^17 fits)
__global__ __launch_bounds__(256) void kA2(const int* __restrict__ edges,
                                           int* __restrict__ bcur,
                                           unsigned* __restrict__ pairs){
  __shared__ int h[NBKT];
  int tid = threadIdx.x;
  for (int i = tid; i < NBKT; i += 256) h[i] = 0;
  __syncthreads();
  int base = blockIdx.x * ACHUNK;
  for (int i = tid; i < ACHUNK; i += 256){
    int j = base + i;
    if (j < N_EDGES) atomicAdd(&h[edges[N_EDGES + j] >> 8], 1);
  }
  __syncthreads();
  for (int i = tid; i < NBKT; i += 256)
    h[i] = h[i] ? atomicAdd(&bcur[i], h[i]) : 0;   // h becomes block-local cursor
  __syncthreads();
  for (int i = tid; i < ACHUNK; i += 256){
    int j = base + i;
    if (j < N_EDGES){
      int s = edges[j], d = edges[N_EDGES + j];
      int pos = atomicAdd(&h[d >> 8], 1);
      pairs[pos] = ((unsigned)s << 8) | (unsigned)(d & 255);
    }
  }
}

// ---------------- bucket counting sort -> CSR --------------------

__global__ __launch_bounds__(256) void k_kb(const unsigned* __restrict__ pairs,
                                            const int* __restrict__ bbase,
                                            int* __restrict__ off,
                                            int* __restrict__ deg,
                                            float* __restrict__ invdeg,
                                            int* __restrict__ cols){
  __shared__ int hh[768];
  int* h = hh; int* s = hh + 256; int* cur = hh + 512;
  int bkt = blockIdx.x, tid = threadIdx.x;
  int base = bbase[bkt], cnt = bbase[bkt + 1] - base;
  int nodeBase = bkt << 8;

  h[tid] = 0; __syncthreads();
  for (int i = tid; i < cnt; i += 256){
    unsigned p = pairs[base + i];
    atomicAdd(&h[p & 255u], 1);
  }
  __syncthreads();
  int v = h[tid];
  s[tid] = v; __syncthreads();
  for (int d = 1; d < 256; d <<= 1){
    int t = (tid >= d) ? s[tid - d] : 0;
    __syncthreads();
    s[tid] += t;
    __syncthreads();
  }
  int excl = s[tid] - v;
  int node = nodeBase + tid;
  if (node < N_NODES){
    off[node] = base + excl;
    deg[node] = v;
    invdeg[node] = 1.0f / (float)(v > 1 ? v : 1);
  }
  cur[tid] = base + excl;
  __syncthreads();
  for (int i = tid; i < cnt; i += 256){
    unsigned p = pairs[base + i];
    int pos = atomicAdd(&cur[p & 255u], 1);
    cols[pos] = (int)(p >> 8);
  }
}

// ---------------- per-node mean of neighbor rows (128-wide, bf16 out) ----------

__device__ __forceinline__ uint4 agg_mean128(int node, int f,
                                             const int* __restrict__ off,
                                             const int* __restrict__ deg,
                                             const float* __restrict__ invdeg,
                                             const int* __restrict__ cols,
                                             const u16* __restrict__ H){
  int start = off[node], cnt = deg[node];
  float inv = invdeg[node];
  const uint4* __restrict__ H4 = (const uint4*)H;     // row = 16 uint4
  const int* __restrict__ cb = cols + start;

  float2 a0 = make_float2(0.f, 0.f), a1 = a0, a2 = a0, a3 = a0;
  auto accum = [&](uint4 u){
    a0.x += lo_bf(u.x); a0.y += hi_bf(u.x);
    a1.x += lo_bf(u.y); a1.y += hi_bf(u.y);
    a2.x += lo_bf(u.z); a2.y += hi_bf(u.z);
    a3.x += lo_bf(u.w); a3.y += hi_bf(u.w);
  };

  int e = 0;
  int nfull = cnt & ~7;
  for (; e < nfull; e += 8){
    int s[8];
    #pragma unroll
    for (int j = 0; j < 8; ++j) s[j] = cb[e + j];
    uint4 u[8];
    #pragma unroll
    for (int j = 0; j < 8; ++j) u[j] = H4[(size_t)s[j] * 16 + f];
    #pragma unroll
    for (int j = 0; j < 8; ++j) accum(u[j]);
  }
  if (e < cnt){                                 // masked 8-granule tail (<=1 iter)
    int last = cnt - 1;
    int s[8];
    #pragma unroll
    for (int j = 0; j < 8; ++j){
      int i = e + j;
      s[j] = cb[i < last ? i : last];
    }
    uint4 u[8];
    #pragma unroll
    for (int j = 0; j < 8; ++j) u[j] = H4[(size_t)s[j] * 16 + f];
    #pragma unroll
    for (int j = 0; j < 8; ++j){
      if (e + j > last) u[j] = make_uint4(0u, 0u, 0u, 0u);
      accum(u[j]);
    }
  }

  uint4 ov;
  ov.x = (unsigned)f2bf(inv * a0.x) | ((unsigned)f2bf(inv * a0.y) << 16);
  ov.y = (unsigned)f2bf(inv * a1.x) | ((unsigned)f2bf(inv * a1.y) << 16);
  ov.z = (unsigned)f2bf(inv * a2.x) | ((unsigned)f2bf(inv * a2.y) << 16);
  ov.w = (unsigned)f2bf(inv * a3.x) | ((unsigned)f2bf(inv * a3.y) << 16);
  return ov;
}

// ---------------- fused layer: gather mean(h) + [h|m] @ [Wl;Wr] + b ------------
// 32-row tile, 256 threads (4 waves), As = 32 x 264 u16 = 16.9 KB ->
// 6 blocks/CU x 4 waves = 24 waves/CU target occupancy. K=256 single phase,
// B fragments read straight from global WT (L1/L2-hot, shared by all blocks).

template<int N1, int RELU, int F32OUT>
__global__ __launch_bounds__(256, 6) void k_aggemm(const int* __restrict__ off,
                                                   const int* __restrict__ deg,
                                                   const float* __restrict__ invdeg,
                                                   const int* __restrict__ cols,
                                                   const u16* __restrict__ Hin,
                                                   const u16* __restrict__ WT,
                                                   const float* __restrict__ bias,
                                                   void* __restrict__ out_){
  __shared__ u16 As[32 * 264];                   // row: [h(128) | m(128) | pad 8]
  int tid = threadIdx.x;
  int qq = tid >> 4, f = tid & 15;               // qq in [0,16)
  int rowBase = blockIdx.x * 32;
  const uint4* __restrict__ H4 = (const uint4*)Hin;

  #pragma unroll
  for (int pass = 0; pass < 2; ++pass){
    int lr = pass * 16 + qq;                     // local row 0..31
    int node = rowBase + lr;
    uint4 hv = make_uint4(0u, 0u, 0u, 0u);
    uint4 mv = make_uint4(0u, 0u, 0u, 0u);
    if (node < N_NODES){
      hv = H4[(size_t)node * 16 + f];            // issued early, hides under agg
      mv = agg_mean128(node, f, off, deg, invdeg, cols, Hin);
    }
    ((uint4*)As)[lr * 33 + f]      = hv;
    ((uint4*)As)[lr * 33 + 16 + f] = mv;
  }
  __syncthreads();

  // GEMM: C[32 x N1] = As[32 x 256] @ WT^T, wave w owns cols [w*N1/4, (w+1)*N1/4)
  const int lane = tid & 63, wave = tid >> 6;    // wave 0..3
  const int quad = lane >> 4, l15 = lane & 15;
  constexpr int NI = N1 / 64;                    // 2 for N1=128, 1 for N1=64
  constexpr int WS = N1 / 4;                     // wave col-strip

  v4f acc[2][NI] = {};
  #pragma unroll
  for (int kt = 0; kt < 8; ++kt){
    int ko = kt * 32 + quad * 8;
    v8s a0 = *(const v8s*)&As[(l15     ) * 264 + ko];
    v8s a1 = *(const v8s*)&As[(l15 + 16) * 264 + ko];
    #pragma unroll
    for (int ni = 0; ni < NI; ++ni){
      int brow = wave * WS + ni * 16 + l15;
      v8s b = *(const v8s*)&WT[(size_t)brow * 256 + ko];
      acc[0][ni] = __builtin_amdgcn_mfma_f32_16x16x32_bf16(a0, b, acc[0][ni], 0, 0, 0);
      acc[1][ni] = __builtin_amdgcn_mfma_f32_16x16x32_bf16(a1, b, acc[1][ni], 0, 0, 0);
    }
  }

  #pragma unroll
  for (int mi = 0; mi < 2; ++mi)
    #pragma unroll
    for (int ni = 0; ni < NI; ++ni)
      #pragma unroll
      for (int r = 0; r < 4; ++r){
        int grow = rowBase + mi * 16 + quad * 4 + r;
        int gcol = wave * WS + ni * 16 + l15;
        if (grow < N_NODES){
          float v = acc[mi][ni][r] + bias[gcol];
          if (F32OUT){
            ((float*)out_)[(size_t)grow * N1 + gcol] = v;
          } else {
            if (RELU) v = fmaxf(v, 0.f);
            ((u16*)out_)[(size_t)grow * N1 + gcol] = f2bf(v);
          }
        }
      }
}

// ---------------- launch ----------------

extern "C" void kernel_launch(void* const* d_in, const int* in_sizes, int n_in,
                              void* d_out, int out_size, void* d_ws, size_t ws_size,
                              hipStream_t stream) {
  const float* x     = (const float*)d_in[0];
  const int*   edges = (const int*)  d_in[1];
  const float* Wl1 = (const float*)d_in[2];
  const float* Wr1 = (const float*)d_in[3];
  const float* b1  = (const float*)d_in[4];
  const float* Wl2 = (const float*)d_in[5];
  const float* Wr2 = (const float*)d_in[6];
  const float* b2  = (const float*)d_in[7];
  const float* Wl3 = (const float*)d_in[8];
  const float* Wr3 = (const float*)d_in[9];
  const float* b3  = (const float*)d_in[10];

  char* ws = (char*)d_ws;
  size_t o = 0;
  auto alloc = [&](size_t bytes) -> void* {
    void* p = ws + o;
    o += (bytes + 255) & ~(size_t)255;
    return p;
  };
  int*      deg    = (int*)     alloc(N_NODES * 4);
  int*      off    = (int*)     alloc(N_NODES * 4);
  float*    invdeg = (float*)   alloc(N_NODES * 4);
  int*      bpart  = (int*)     alloc((size_t)AB * NBKT * 4);
  int*      bbase  = (int*)     alloc((NBKT + 1) * 4);
  int*      bcur   = (int*)     alloc(NBKT * 4);
  unsigned* pairs  = (unsigned*)alloc((size_t)N_EDGES * 4);
  int*      cols   = (int*)     alloc(N_EDGES * 4);
  u16*      Xb     = (u16*)     alloc((size_t)N_NODES * 128 * 2);
  u16*      H1     = (u16*)     alloc((size_t)N_NODES * 128 * 2);
  u16*      H2     = (u16*)     alloc((size_t)N_NODES * 128 * 2);
  u16*      WT1    = (u16*)     alloc(128 * 256 * 2);
  u16*      WT2    = (u16*)     alloc(128 * 256 * 2);
  u16*      WT3    = (u16*)     alloc(64 * 256 * 2);

  // 1. prep (cast + wprep x3) + A1 partial histograms
  k_prep_a1<<<CASTB + 320 + AB, 256, 0, stream>>>(x, Xb, Wl1, Wr1, Wl2, Wr2,
                                                  Wl3, Wr3, WT1, WT2, WT3,
                                                  edges, bpart);
  // 2. reduce + scan bucket counts
  k_scanb<<<1, 256, 0, stream>>>(bpart, bbase, bcur);
  // 3. bucket-major pair scatter (packed u32 pairs)
  kA2<<<AB, 256, 0, stream>>>(edges, bcur, pairs);
  // 4. bucket counting sort -> CSR
  k_kb<<<NBKT, 256, 0, stream>>>(pairs, bbase, off, deg, invdeg, cols);
  // 5. layer 1: h1 = relu([x | mean x] @ [Wl1;Wr1] + b1)
  k_aggemm<128, 1, 0><<<MG32, 256, 0, stream>>>(off, deg, invdeg, cols,
                                                Xb, WT1, b1, H1);
  // 6. layer 2: h2 = relu([h1 | mean h1] @ [Wl2;Wr2] + b2)
  k_aggemm<128, 1, 0><<<MG32, 256, 0, stream>>>(off, deg, invdeg, cols,
                                                H1, WT2, b2, H2);
  // 7. layer 3: out = [h2 | mean h2] @ [Wl3;Wr3] + b3   (fp32, no relu)
  k_aggemm<64, 0, 1><<<MG32, 256, 0, stream>>>(off, deg, invdeg, cols,
                                               H2, WT3, b3, d_out);
}

// Round 4
// 245.334 us; speedup vs baseline: 1.0635x; 1.0635x over previous
//
#include <hip/hip_runtime.h>
#include <hip/hip_bf16.h>

#define N_NODES 50000
#define N_EDGES 800000
#define NBKT 196           // ceil(50000/256) buckets of 256 nodes
#define ACHUNK 4096        // edges per block in binning kernels
#define AB 196             // ceil(800000/4096) histogram blocks
#define CASTB 6250         // 50000*128/4 float4 chunks / 256 threads
#define MG32 1563          // ceil(50000/32) aggemm row-tiles

typedef unsigned short u16;
typedef short v8s __attribute__((ext_vector_type(8)));
typedef float v4f __attribute__((ext_vector_type(4)));

__device__ __forceinline__ u16 f2bf(float f){
  union { float f; unsigned u; } x; x.f = f;
  unsigned u = x.u;
  return (u16)((u + 0x7FFFu + ((u >> 16) & 1u)) >> 16);   // RNE
}
__device__ __forceinline__ float lo_bf(unsigned u){
  union { unsigned u; float f; } x; x.u = u << 16; return x.f;
}
__device__ __forceinline__ float hi_bf(unsigned u){
  union { unsigned u; float f; } x; x.u = u & 0xffff0000u; return x.f;
}

// ---------------- fused prep: cast x->bf16, 3x weight transpose, A1 hist -------
// WT layout (stacked-K): WT[n*256 + k] = (k<128 ? Wl[k][n] : Wr[k-128][n]).
// out = [h | mean_h] @ [Wl; Wr]  — aggregation commutes with the linear map.

__device__ __forceinline__ void wprep(const float* __restrict__ Wl,
                                      const float* __restrict__ Wr,
                                      u16* __restrict__ WT, int N1, int idx){
  int n = idx >> 8, k = idx & 255;
  float v = (k < 128) ? Wl[k * N1 + n] : Wr[(k - 128) * N1 + n];
  WT[n * 256 + k] = f2bf(v);
}

__global__ __launch_bounds__(256) void k_prep_a1(const float* __restrict__ x,
                                                 u16* __restrict__ Xb,
                                                 const float* __restrict__ Wl1,
                                                 const float* __restrict__ Wr1,
                                                 const float* __restrict__ Wl2,
                                                 const float* __restrict__ Wr2,
                                                 const float* __restrict__ Wl3,
                                                 const float* __restrict__ Wr3,
                                                 u16* __restrict__ WT1,
                                                 u16* __restrict__ WT2,
                                                 u16* __restrict__ WT3,
                                                 const int* __restrict__ edges,
                                                 int* __restrict__ bcnt){
  __shared__ int h[NBKT];
  int b = blockIdx.x, tid = threadIdx.x;
  if (b < CASTB){
    int i = b * 256 + tid;                       // exact: 6250*256 = 1.6M float4
    float4 v = ((const float4*)x)[i];
    ((ushort4*)Xb)[i] = make_ushort4(f2bf(v.x), f2bf(v.y), f2bf(v.z), f2bf(v.w));
  } else if (b < CASTB + 128){
    wprep(Wl1, Wr1, WT1, 128, (b - CASTB) * 256 + tid);        // 128*256 elems
  } else if (b < CASTB + 256){
    wprep(Wl2, Wr2, WT2, 128, (b - CASTB - 128) * 256 + tid);  // 128*256 elems
  } else if (b < CASTB + 320){
    wprep(Wl3, Wr3, WT3, 64, (b - CASTB - 256) * 256 + tid);   // 64*256 elems
  } else {
    int ab = b - (CASTB + 320);                  // 0..AB-1
    for (int i = tid; i < NBKT; i += 256) h[i] = 0;
    __syncthreads();
    int base = ab * ACHUNK;
    for (int i = tid; i < ACHUNK; i += 256){
      int j = base + i;
      if (j < N_EDGES) atomicAdd(&h[edges[N_EDGES + j] >> 8], 1);
    }
    __syncthreads();
    for (int i = tid; i < NBKT; i += 256)
      if (h[i]) atomicAdd(&bcnt[i], h[i]);       // global hist: no bpart matrix
  }
}

// scan bcnt -> bbase (exclusive, +total), init bcur.  Coalesced single read.
__global__ __launch_bounds__(256) void k_scanb(const int* __restrict__ bcnt,
                                               int* __restrict__ bbase,
                                               int* __restrict__ bcur){
  __shared__ int s[256];
  int tid = threadIdx.x;
  int v = (tid < NBKT) ? bcnt[tid] : 0;
  s[tid] = v; __syncthreads();
  for (int d = 1; d < 256; d <<= 1){
    int t = (tid >= d) ? s[tid - d] : 0;
    __syncthreads();
    s[tid] += t;
    __syncthreads();
  }
  if (tid < NBKT){ bbase[tid] = s[tid] - v; bcur[tid] = s[tid] - v; }
  if (tid == NBKT - 1) bbase[NBKT] = s[tid];
}

// bucket-major scatter; pair packed as (src<<8) | (dst & 255)  (src<2^17 fits)
__global__ __launch_bounds__(256) void kA2(const int* __restrict__ edges,
                                           int* __restrict__ bcur,
                                           unsigned* __restrict__ pairs){
  __shared__ int h[NBKT];
  int tid = threadIdx.x;
  for (int i = tid; i < NBKT; i += 256) h[i] = 0;
  __syncthreads();
  int base = blockIdx.x * ACHUNK;
  for (int i = tid; i < ACHUNK; i += 256){
    int j = base + i;
    if (j < N_EDGES) atomicAdd(&h[edges[N_EDGES + j] >> 8], 1);
  }
  __syncthreads();
  for (int i = tid; i < NBKT; i += 256)
    h[i] = h[i] ? atomicAdd(&bcur[i], h[i]) : 0;   // h becomes block-local cursor
  __syncthreads();
  for (int i = tid; i < ACHUNK; i += 256){
    int j = base + i;
    if (j < N_EDGES){
      int s = edges[j], d = edges[N_EDGES + j];
      int pos = atomicAdd(&h[d >> 8], 1);
      pairs[pos] = ((unsigned)s << 8) | (unsigned)(d & 255);
    }
  }
}

// ---------------- bucket counting sort -> CSR --------------------

__global__ __launch_bounds__(256) void k_kb(const unsigned* __restrict__ pairs,
                                            const int* __restrict__ bbase,
                                            int* __restrict__ off,
                                            int* __restrict__ deg,
                                            float* __restrict__ invdeg,
                                            int* __restrict__ cols){
  __shared__ int hh[768];
  int* h = hh; int* s = hh + 256; int* cur = hh + 512;
  int bkt = blockIdx.x, tid = threadIdx.x;
  int base = bbase[bkt], cnt = bbase[bkt + 1] - base;
  int nodeBase = bkt << 8;

  h[tid] = 0; __syncthreads();
  for (int i = tid; i < cnt; i += 256){
    unsigned p = pairs[base + i];
    atomicAdd(&h[p & 255u], 1);
  }
  __syncthreads();
  int v = h[tid];
  s[tid] = v; __syncthreads();
  for (int d = 1; d < 256; d <<= 1){
    int t = (tid >= d) ? s[tid - d] : 0;
    __syncthreads();
    s[tid] += t;
    __syncthreads();
  }
  int excl = s[tid] - v;
  int node = nodeBase + tid;
  if (node < N_NODES){
    off[node] = base + excl;
    deg[node] = v;
    invdeg[node] = 1.0f / (float)(v > 1 ? v : 1);
  }
  cur[tid] = base + excl;
  __syncthreads();
  for (int i = tid; i < cnt; i += 256){
    unsigned p = pairs[base + i];
    int pos = atomicAdd(&cur[p & 255u], 1);
    cols[pos] = (int)(p >> 8);
  }
}

// ---------------- per-node mean of neighbor rows (128-wide, bf16 out) ----------

__device__ __forceinline__ uint4 agg_mean128(int node, int f,
                                             const int* __restrict__ off,
                                             const int* __restrict__ deg,
                                             const float* __restrict__ invdeg,
                                             const int* __restrict__ cols,
                                             const u16* __restrict__ H){
  int start = off[node], cnt = deg[node];
  float inv = invdeg[node];
  const uint4* __restrict__ H4 = (const uint4*)H;     // row = 16 uint4
  const int* __restrict__ cb = cols + start;

  float2 a0 = make_float2(0.f, 0.f), a1 = a0, a2 = a0, a3 = a0;
  auto accum = [&](uint4 u){
    a0.x += lo_bf(u.x); a0.y += hi_bf(u.x);
    a1.x += lo_bf(u.y); a1.y += hi_bf(u.y);
    a2.x += lo_bf(u.z); a2.y += hi_bf(u.z);
    a3.x += lo_bf(u.w); a3.y += hi_bf(u.w);
  };

  int e = 0;
  int nfull = cnt & ~7;
  for (; e < nfull; e += 8){
    int s[8];
    #pragma unroll
    for (int j = 0; j < 8; ++j) s[j] = cb[e + j];
    uint4 u[8];
    #pragma unroll
    for (int j = 0; j < 8; ++j) u[j] = H4[(size_t)s[j] * 16 + f];
    #pragma unroll
    for (int j = 0; j < 8; ++j) accum(u[j]);
  }
  if (e < cnt){                                 // masked 8-granule tail (<=1 iter)
    int last = cnt - 1;
    int s[8];
    #pragma unroll
    for (int j = 0; j < 8; ++j){
      int i = e + j;
      s[j] = cb[i < last ? i : last];
    }
    uint4 u[8];
    #pragma unroll
    for (int j = 0; j < 8; ++j) u[j] = H4[(size_t)s[j] * 16 + f];
    #pragma unroll
    for (int j = 0; j < 8; ++j){
      if (e + j > last) u[j] = make_uint4(0u, 0u, 0u, 0u);
      accum(u[j]);
    }
  }

  uint4 ov;
  ov.x = (unsigned)f2bf(inv * a0.x) | ((unsigned)f2bf(inv * a0.y) << 16);
  ov.y = (unsigned)f2bf(inv * a1.x) | ((unsigned)f2bf(inv * a1.y) << 16);
  ov.z = (unsigned)f2bf(inv * a2.x) | ((unsigned)f2bf(inv * a2.y) << 16);
  ov.w = (unsigned)f2bf(inv * a3.x) | ((unsigned)f2bf(inv * a3.y) << 16);
  return ov;
}

// ---------------- fused layer: gather mean(h) + [h|m] @ [Wl;Wr] + b ------------
// 32-row tile, 256 threads (4 waves), As = 32 x 264 u16 = 16.9 KB.
// PROJ=1 additionally computes Y3 = relu(h_out) @ Wr3 for the next layer's
// 64-wide gather (aggregation commutes with the linear map).

template<int RELU, int PROJ>
__global__ __launch_bounds__(256, 6) void k_aggemm(const int* __restrict__ off,
                                                   const int* __restrict__ deg,
                                                   const float* __restrict__ invdeg,
                                                   const int* __restrict__ cols,
                                                   const u16* __restrict__ Hin,
                                                   const u16* __restrict__ WT,
                                                   const float* __restrict__ bias,
                                                   u16* __restrict__ Hout,
                                                   const u16* __restrict__ WTp,
                                                   u16* __restrict__ Yout){
  __shared__ u16 As[32 * 264];                   // row: [h(128) | m(128) | pad 8]
  int tid = threadIdx.x;
  int qq = tid >> 4, f = tid & 15;               // qq in [0,16)
  int rowBase = blockIdx.x * 32;
  const uint4* __restrict__ H4 = (const uint4*)Hin;

  #pragma unroll
  for (int pass = 0; pass < 2; ++pass){
    int lr = pass * 16 + qq;                     // local row 0..31
    int node = rowBase + lr;
    uint4 hv = make_uint4(0u, 0u, 0u, 0u);
    uint4 mv = make_uint4(0u, 0u, 0u, 0u);
    if (node < N_NODES){
      hv = H4[(size_t)node * 16 + f];            // issued early, hides under agg
      mv = agg_mean128(node, f, off, deg, invdeg, cols, Hin);
    }
    ((uint4*)As)[lr * 33 + f]      = hv;
    ((uint4*)As)[lr * 33 + 16 + f] = mv;
  }
  __syncthreads();

  // GEMM: C[32 x 128] = As[32 x 256] @ WT^T, wave w owns cols [w*32,(w+1)*32)
  const int lane = tid & 63, wave = tid >> 6;    // wave 0..3
  const int quad = lane >> 4, l15 = lane & 15;

  v4f acc[2][2] = {};
  #pragma unroll
  for (int kt = 0; kt < 8; ++kt){
    int ko = kt * 32 + quad * 8;
    v8s a0 = *(const v8s*)&As[(l15     ) * 264 + ko];
    v8s a1 = *(const v8s*)&As[(l15 + 16) * 264 + ko];
    #pragma unroll
    for (int ni = 0; ni < 2; ++ni){
      int brow = wave * 32 + ni * 16 + l15;
      v8s b = *(const v8s*)&WT[(size_t)brow * 256 + ko];
      acc[0][ni] = __builtin_amdgcn_mfma_f32_16x16x32_bf16(a0, b, acc[0][ni], 0, 0, 0);
      acc[1][ni] = __builtin_amdgcn_mfma_f32_16x16x32_bf16(a1, b, acc[1][ni], 0, 0, 0);
    }
  }

  if (PROJ) __syncthreads();                     // all As reads done before reuse

  #pragma unroll
  for (int mi = 0; mi < 2; ++mi)
    #pragma unroll
    for (int ni = 0; ni < 2; ++ni)
      #pragma unroll
      for (int r = 0; r < 4; ++r){
        int lrow = mi * 16 + quad * 4 + r;
        int grow = rowBase + lrow;
        int gcol = wave * 32 + ni * 16 + l15;
        float v = acc[mi][ni][r] + bias[gcol];
        if (RELU) v = fmaxf(v, 0.f);
        u16 bv = f2bf(v);
        if (grow < N_NODES) Hout[(size_t)grow * 128 + gcol] = bv;
        if (PROJ) As[lrow * 136 + gcol] = bv;    // h tile for Y projection
      }

  if (PROJ){
    __syncthreads();
    // Y[32 x 64] = h[32 x 128] @ Wr3^T; wave w owns cols [w*16,(w+1)*16)
    v4f a2[2] = {};
    int brow = wave * 16 + l15;
    #pragma unroll
    for (int kt = 0; kt < 4; ++kt){
      int ko = kt * 32 + quad * 8;
      v8s a0 = *(const v8s*)&As[(l15     ) * 136 + ko];
      v8s a1 = *(const v8s*)&As[(l15 + 16) * 136 + ko];
      v8s b  = *(const v8s*)&WTp[(size_t)brow * 256 + 128 + ko];  // Wr half
      a2[0] = __builtin_amdgcn_mfma_f32_16x16x32_bf16(a0, b, a2[0], 0, 0, 0);
      a2[1] = __builtin_amdgcn_mfma_f32_16x16x32_bf16(a1, b, a2[1], 0, 0, 0);
    }
    #pragma unroll
    for (int mi = 0; mi < 2; ++mi)
      #pragma unroll
      for (int r = 0; r < 4; ++r){
        int grow = rowBase + mi * 16 + quad * 4 + r;
        int gcol = wave * 16 + l15;
        if (grow < N_NODES)
          Yout[(size_t)grow * 64 + gcol] = f2bf(a2[mi][r]);
      }
  }
}

// ---------------- final layer: gather mean(Y) 64-wide + h2 @ Wl3 + b, fp32 -----

__global__ __launch_bounds__(256, 6) void k_out(const int* __restrict__ off,
                                                const int* __restrict__ deg,
                                                const float* __restrict__ invdeg,
                                                const int* __restrict__ cols,
                                                const u16* __restrict__ H2,
                                                const u16* __restrict__ Y3,
                                                const u16* __restrict__ WT3,
                                                const float* __restrict__ bias,
                                                float* __restrict__ out){
  __shared__ u16 As[32 * 136];                   // h2 tile
  __shared__ float Ms[32 * 72];                  // mean(Y) tile, padded
  int tid = threadIdx.x;
  int rowBase = blockIdx.x * 32;

  // stage h2 tile (coalesced)
  #pragma unroll
  for (int it = 0; it < 2; ++it){
    int chunk = tid + it * 256;
    int r = chunk >> 4, cseg = chunk & 15;
    int gr = rowBase + r;
    uint4 va = make_uint4(0u, 0u, 0u, 0u);
    if (gr < N_NODES) va = ((const uint4*)(H2 + (size_t)gr * 128))[cseg];
    ((uint4*)As)[r * 17 + cseg] = va;
  }

  // gather mean(Y3): 8 lanes/node, 32 nodes/block
  int oo = tid >> 3, f = tid & 7;
  int node = rowBase + oo;
  if (node < N_NODES){
    int start = off[node], cnt = deg[node];
    float inv = invdeg[node];
    const uint4* __restrict__ Y4 = (const uint4*)Y3;   // row = 8 uint4
    const int* __restrict__ cb = cols + start;

    float2 a0 = make_float2(0.f, 0.f), a1 = a0, a2 = a0, a3 = a0;
    auto accum = [&](uint4 u){
      a0.x += lo_bf(u.x); a0.y += hi_bf(u.x);
      a1.x += lo_bf(u.y); a1.y += hi_bf(u.y);
      a2.x += lo_bf(u.z); a2.y += hi_bf(u.z);
      a3.x += lo_bf(u.w); a3.y += hi_bf(u.w);
    };

    int e = 0;
    int nfull = cnt & ~7;
    for (; e < nfull; e += 8){
      int s[8];
      #pragma unroll
      for (int j = 0; j < 8; ++j) s[j] = cb[e + j];
      uint4 u[8];
      #pragma unroll
      for (int j = 0; j < 8; ++j) u[j] = Y4[(size_t)s[j] * 8 + f];
      #pragma unroll
      for (int j = 0; j < 8; ++j) accum(u[j]);
    }
    if (e < cnt){
      int last = cnt - 1;
      int s[8];
      #pragma unroll
      for (int j = 0; j < 8; ++j){
        int i = e + j;
        s[j] = cb[i < last ? i : last];
      }
      uint4 u[8];
      #pragma unroll
      for (int j = 0; j < 8; ++j) u[j] = Y4[(size_t)s[j] * 8 + f];
      #pragma unroll
      for (int j = 0; j < 8; ++j){
        if (e + j > last) u[j] = make_uint4(0u, 0u, 0u, 0u);
        accum(u[j]);
      }
    }
    float* m = &Ms[oo * 72 + f * 8];
    m[0] = inv * a0.x; m[1] = inv * a0.y;
    m[2] = inv * a1.x; m[3] = inv * a1.y;
    m[4] = inv * a2.x; m[5] = inv * a2.y;
    m[6] = inv * a3.x; m[7] = inv * a3.y;
  }
  __syncthreads();

  // GEMM: C[32 x 64] = h2[32 x 128] @ Wl3^T; wave w owns cols [w*16,(w+1)*16)
  const int lane = tid & 63, wave = tid >> 6;
  const int quad = lane >> 4, l15 = lane & 15;
  int brow = wave * 16 + l15;

  v4f acc[2] = {};
  #pragma unroll
  for (int kt = 0; kt < 4; ++kt){
    int ko = kt * 32 + quad * 8;
    v8s a0 = *(const v8s*)&As[(l15     ) * 136 + ko];
    v8s a1 = *(const v8s*)&As[(l15 + 16) * 136 + ko];
    v8s b  = *(const v8s*)&WT3[(size_t)brow * 256 + ko];   // Wl half
    acc[0] = __builtin_amdgcn_mfma_f32_16x16x32_bf16(a0, b, acc[0], 0, 0, 0);
    acc[1] = __builtin_amdgcn_mfma_f32_16x16x32_bf16(a1, b, acc[1], 0, 0, 0);
  }
  #pragma unroll
  for (int mi = 0; mi < 2; ++mi)
    #pragma unroll
    for (int r = 0; r < 4; ++r){
      int lrow = mi * 16 + quad * 4 + r;
      int grow = rowBase + lrow;
      int gcol = wave * 16 + l15;
      if (grow < N_NODES)
        out[(size_t)grow * 64 + gcol] = acc[mi][r] + bias[gcol] + Ms[lrow * 72 + gcol];
    }
}

// ---------------- launch ----------------

extern "C" void kernel_launch(void* const* d_in, const int* in_sizes, int n_in,
                              void* d_out, int out_size, void* d_ws, size_t ws_size,
                              hipStream_t stream) {
  const float* x     = (const float*)d_in[0];
  const int*   edges = (const int*)  d_in[1];
  const float* Wl1 = (const float*)d_in[2];
  const float* Wr1 = (const float*)d_in[3];
  const float* b1  = (const float*)d_in[4];
  const float* Wl2 = (const float*)d_in[5];
  const float* Wr2 = (const float*)d_in[6];
  const float* b2  = (const float*)d_in[7];
  const float* Wl3 = (const float*)d_in[8];
  const float* Wr3 = (const float*)d_in[9];
  const float* b3  = (const float*)d_in[10];

  char* ws = (char*)d_ws;
  size_t o = 0;
  auto alloc = [&](size_t bytes) -> void* {
    void* p = ws + o;
    o += (bytes + 255) & ~(size_t)255;
    return p;
  };
  int*      deg    = (int*)     alloc(N_NODES * 4);
  int*      off    = (int*)     alloc(N_NODES * 4);
  float*    invdeg = (float*)   alloc(N_NODES * 4);
  int*      bcnt   = (int*)     alloc(NBKT * 4);
  int*      bbase  = (int*)     alloc((NBKT + 1) * 4);
  int*      bcur   = (int*)     alloc(NBKT * 4);
  unsigned* pairs  = (unsigned*)alloc((size_t)N_EDGES * 4);
  int*      cols   = (int*)     alloc(N_EDGES * 4);
  u16*      Xb     = (u16*)     alloc((size_t)N_NODES * 128 * 2);
  u16*      H1     = (u16*)     alloc((size_t)N_NODES * 128 * 2);
  u16*      H2     = (u16*)     alloc((size_t)N_NODES * 128 * 2);
  u16*      Y3     = (u16*)     alloc((size_t)N_NODES * 64 * 2);
  u16*      WT1    = (u16*)     alloc(128 * 256 * 2);
  u16*      WT2    = (u16*)     alloc(128 * 256 * 2);
  u16*      WT3    = (u16*)     alloc(64 * 256 * 2);

  // 0. zero global histogram
  hipMemsetAsync(bcnt, 0, NBKT * 4, stream);
  // 1. prep (cast + wprep x3) + A1 histogram (global atomics)
  k_prep_a1<<<CASTB + 320 + AB, 256, 0, stream>>>(x, Xb, Wl1, Wr1, Wl2, Wr2,
                                                  Wl3, Wr3, WT1, WT2, WT3,
                                                  edges, bcnt);
  // 2. scan bucket counts (coalesced single read)
  k_scanb<<<1, 256, 0, stream>>>(bcnt, bbase, bcur);
  // 3. bucket-major pair scatter (packed u32 pairs)
  kA2<<<AB, 256, 0, stream>>>(edges, bcur, pairs);
  // 4. bucket counting sort -> CSR
  k_kb<<<NBKT, 256, 0, stream>>>(pairs, bbase, off, deg, invdeg, cols);
  // 5. layer 1: h1 = relu([x | mean x] @ [Wl1;Wr1] + b1)
  k_aggemm<1, 0><<<MG32, 256, 0, stream>>>(off, deg, invdeg, cols,
                                           Xb, WT1, b1, H1, WT3, Y3);
  // 6. layer 2: h2 = relu([h1 | mean h1] @ [Wl2;Wr2] + b2), + Y3 = h2 @ Wr3
  k_aggemm<1, 1><<<MG32, 256, 0, stream>>>(off, deg, invdeg, cols,
                                           H1, WT2, b2, H2, WT3, Y3);
  // 7. layer 3: out = h2 @ Wl3 + mean(Y3) + b3   (fp32, 64-wide gather)
  k_out<<<MG32, 256, 0, stream>>>(off, deg, invdeg, cols, H2, Y3, WT3, b3,
                                  (float*)d_out);
}